// Round 1
// baseline (678.095 us; speedup 1.0000x reference)
//
#include <hip/hip_runtime.h>
#include <hip/hip_bf16.h>

#define NFEAT 768
#define NHID 128
#define NEG_SLOPE 0.2f
#define SM_EPS 1e-16f

typedef __attribute__((ext_vector_type(8))) short bf16x8s;
typedef __attribute__((ext_vector_type(4))) float f32x4;

__device__ inline float bf2f(unsigned short u) {
    return __uint_as_float(((unsigned int)u) << 16);
}
__device__ inline unsigned short f2bf(float f) {
    unsigned int u = __float_as_uint(f);
    u += 0x7fffu + ((u >> 16) & 1u);   // round-to-nearest-even
    return (unsigned short)(u >> 16);
}

// ---------------------------------------------------------------- prep: W^T -> bf16
__global__ void prep_wt(const float* __restrict__ W, unsigned short* __restrict__ Wt) {
    int idx = blockIdx.x * 256 + threadIdx.x;       // over 768*128
    if (idx >= NFEAT * NHID) return;
    int k = idx >> 7, n = idx & 127;
    Wt[(size_t)n * NFEAT + k] = f2bf(W[idx]);
}

// ---------------------------------------------------------------- h = x @ W  (bf16 MFMA)
// block 256 = 4 waves (2x2), tile 128x128, BK=32, LDS stride 40 (pad)
__global__ __launch_bounds__(256) void gemm_xw(const float* __restrict__ x,
                                               const unsigned short* __restrict__ Wt,
                                               unsigned short* __restrict__ hbf, int M) {
    __shared__ unsigned short As[128 * 40];
    __shared__ unsigned short Bs[128 * 40];
    const int tid = threadIdx.x;
    const int lane = tid & 63;
    const int wid = tid >> 6;
    const int wr = wid >> 1, wc = wid & 1;
    const int m0 = blockIdx.x * 128;

    f32x4 acc[4][4] = {};

    const int ar = tid >> 3;          // 0..31
    const int ac = (tid & 7) * 4;     // 0..28
    const int br = tid >> 2;          // 0..63
    const int bc = (tid & 3) * 8;     // 0..24

    for (int k0 = 0; k0 < NFEAT; k0 += 32) {
        // stage A (128x32 fp32 -> bf16)
#pragma unroll
        for (int p = 0; p < 4; ++p) {
            int r = ar + p * 32;
            int gr = m0 + r;
            float4 v;
            if (gr < M) v = *(const float4*)(x + (size_t)gr * NFEAT + k0 + ac);
            else        v = make_float4(0.f, 0.f, 0.f, 0.f);
            ushort4 b;
            b.x = f2bf(v.x); b.y = f2bf(v.y); b.z = f2bf(v.z); b.w = f2bf(v.w);
            *(ushort4*)(&As[r * 40 + ac]) = b;
        }
        // stage B: Wt rows = output cols, contiguous K
#pragma unroll
        for (int p = 0; p < 2; ++p) {
            int r = br + p * 64;
            *(int4*)(&Bs[r * 40 + bc]) = *(const int4*)(Wt + (size_t)r * NFEAT + k0 + bc);
        }
        __syncthreads();

        bf16x8s af[4], bfr[4];
        const int kh = (lane >> 4) * 8;
        const int rr = lane & 15;
#pragma unroll
        for (int m = 0; m < 4; ++m)
            af[m] = *(const bf16x8s*)(&As[(wr * 64 + m * 16 + rr) * 40 + kh]);
#pragma unroll
        for (int n = 0; n < 4; ++n)
            bfr[n] = *(const bf16x8s*)(&Bs[(wc * 64 + n * 16 + rr) * 40 + kh]);
#pragma unroll
        for (int m = 0; m < 4; ++m)
#pragma unroll
            for (int n = 0; n < 4; ++n)
                acc[m][n] = __builtin_amdgcn_mfma_f32_16x16x32_bf16(af[m], bfr[n], acc[m][n], 0, 0, 0);
        __syncthreads();
    }

    const int crow = (lane >> 4) * 4;
    const int ccol = lane & 15;
#pragma unroll
    for (int m = 0; m < 4; ++m) {
#pragma unroll
        for (int j = 0; j < 4; ++j) {
            int gr = m0 + wr * 64 + m * 16 + crow + j;
            if (gr < M) {
#pragma unroll
                for (int n = 0; n < 4; ++n)
                    hbf[(size_t)gr * NHID + wc * 64 + n * 16 + ccol] = f2bf(acc[m][n][j]);
            }
        }
    }
}

// ---------------------------------------------------------------- a_src/a_dst = h . att
__global__ __launch_bounds__(256) void attn_proj(const unsigned short* __restrict__ hbf,
                                                 const float* __restrict__ att_src,
                                                 const float* __restrict__ att_dst,
                                                 float* __restrict__ a_src, float* __restrict__ a_dst,
                                                 int N) {
    int gw = (blockIdx.x * 256 + threadIdx.x) >> 6;
    int lane = threadIdx.x & 63;
    int nw = (gridDim.x * 256) >> 6;
    float as0 = att_src[lane * 2], as1 = att_src[lane * 2 + 1];
    float ad0 = att_dst[lane * 2], ad1 = att_dst[lane * 2 + 1];
    for (int row = gw; row < N; row += nw) {
        ushort2 hv = *(const ushort2*)(hbf + (size_t)row * NHID + lane * 2);
        float h0 = bf2f(hv.x), h1 = bf2f(hv.y);
        float ps = h0 * as0 + h1 * as1;
        float pd = h0 * ad0 + h1 * ad1;
        for (int d = 32; d; d >>= 1) { ps += __shfl_xor(ps, d); pd += __shfl_xor(pd, d); }
        if (lane == 0) { a_src[row] = ps; a_dst[row] = pd; }
    }
}

// ---------------------------------------------------------------- CSR build
__global__ void count_k(const int* __restrict__ edst, int* __restrict__ deg, int E, int N) {
    int i = blockIdx.x * 256 + threadIdx.x;
    if (i >= E + N) return;
    int d = (i < E) ? edst[i] : (i - E);
    atomicAdd(deg + d, 1);
}

__global__ void scan1_k(const int* __restrict__ deg, int* __restrict__ off,
                        int* __restrict__ bsum, int N) {
    __shared__ int s[256];
    int b = blockIdx.x, t = threadIdx.x;
    int base = b * 1024 + t * 4;
    int v[4]; int sum = 0;
#pragma unroll
    for (int i = 0; i < 4; ++i) { int idx = base + i; v[i] = (idx < N) ? deg[idx] : 0; sum += v[i]; }
    s[t] = sum; __syncthreads();
    for (int d = 1; d < 256; d <<= 1) {
        int xo = (t >= d) ? s[t - d] : 0;
        __syncthreads();
        s[t] += xo;
        __syncthreads();
    }
    int run = s[t] - sum;               // exclusive prefix within block
    if (t == 255) bsum[b] = s[255];
#pragma unroll
    for (int i = 0; i < 4; ++i) { int idx = base + i; if (idx < N) off[idx] = run; run += v[i]; }
}

__global__ void scan2_k(const int* __restrict__ bsum, int* __restrict__ boff, int nb) {
    __shared__ int s[128];
    int t = threadIdx.x;
    int v = (t < nb) ? bsum[t] : 0;
    s[t] = v; __syncthreads();
    for (int d = 1; d < 128; d <<= 1) {
        int xo = (t >= d) ? s[t - d] : 0;
        __syncthreads();
        s[t] += xo;
        __syncthreads();
    }
    if (t < nb) boff[t] = s[t] - v;
}

__global__ void scan3_k(int* __restrict__ off, const int* __restrict__ boff,
                        int* __restrict__ cursor, int N) {
    int i = blockIdx.x * 256 + threadIdx.x;
    if (i >= N) return;
    int v = off[i] + boff[i >> 10];
    off[i] = v; cursor[i] = v;
}

__global__ void fill_k(const int* __restrict__ esrc, const int* __restrict__ edst,
                       int* __restrict__ cursor, int* __restrict__ csr, int E, int N) {
    int i = blockIdx.x * 256 + threadIdx.x;
    if (i >= E + N) return;
    int s, d;
    if (i < E) { s = esrc[i]; d = edst[i]; } else { s = i - E; d = i - E; }
    int pos = atomicAdd(cursor + d, 1);
    csr[pos] = s;
}

// ---------------------------------------------------------------- segment softmax + aggregate
// one wave per destination node; lanes over 128 features (2/lane)
__global__ __launch_bounds__(256) void aggregate_k(const int* __restrict__ off,
                                                   const int* __restrict__ deg,
                                                   const int* __restrict__ csr,
                                                   const float* __restrict__ a_src,
                                                   const float* __restrict__ a_dst,
                                                   const unsigned short* __restrict__ hbf,
                                                   const float* __restrict__ b_conv,
                                                   float* __restrict__ hrelu, int N) {
    int wid = threadIdx.x >> 6, lane = threadIdx.x & 63;
    int dst = blockIdx.x * 4 + wid;
    if (dst >= N) return;
    int start = off[dst], cnt = deg[dst];
    float ad = a_dst[dst];

    // pass A: segment max (lanes parallel over edges)
    float m = -1e30f;
    for (int j = lane; j < cnt; j += 64) {
        int s = csr[start + j];
        float e = a_src[s] + ad;
        e = e > 0.f ? e : NEG_SLOPE * e;
        m = fmaxf(m, e);
    }
    for (int d = 32; d; d >>= 1) m = fmaxf(m, __shfl_xor(m, d));

    // pass B: weighted feature accumulation (lanes over features)
    float denom = 0.f, acc0 = 0.f, acc1 = 0.f;
    for (int j = 0; j < cnt; ++j) {
        int s = csr[start + j];
        float e = a_src[s] + ad;
        e = e > 0.f ? e : NEG_SLOPE * e;
        float w = expf(e - m);
        denom += w;
        ushort2 hv = *(const ushort2*)(hbf + (size_t)s * NHID + lane * 2);
        acc0 += w * bf2f(hv.x);
        acc1 += w * bf2f(hv.y);
    }
    float inv = 1.f / (denom + SM_EPS);
    float o0 = acc0 * inv + b_conv[lane * 2];
    float o1 = acc1 * inv + b_conv[lane * 2 + 1];
    hrelu[(size_t)dst * NHID + lane * 2]     = fmaxf(o0, 0.f);
    hrelu[(size_t)dst * NHID + lane * 2 + 1] = fmaxf(o1, 0.f);
}

// ---------------------------------------------------------------- global max pool (batch sorted)
__global__ __launch_bounds__(256) void pool_max(const float* __restrict__ hrelu,
                                                const int* __restrict__ batch,
                                                float* __restrict__ x1, int N) {
    int wid = threadIdx.x >> 6, lane = threadIdx.x & 63;
    int n0 = blockIdx.x * 256 + wid * 64;
    if (n0 >= N) return;
    int gcur = batch[n0];
    float v0 = 0.f, v1 = 0.f;
    int end = min(n0 + 64, N);
    for (int n = n0; n < end; ++n) {
        int g = batch[n];
        if (g != gcur) {
            atomicMax((int*)&x1[gcur * NHID + lane * 2],     __float_as_int(v0));
            atomicMax((int*)&x1[gcur * NHID + lane * 2 + 1], __float_as_int(v1));
            v0 = v1 = 0.f; gcur = g;
        }
        float2 hv = *(const float2*)(hrelu + (size_t)n * NHID + lane * 2);
        v0 = fmaxf(v0, hv.x); v1 = fmaxf(v1, hv.y);
    }
    atomicMax((int*)&x1[gcur * NHID + lane * 2],     __float_as_int(v0));
    atomicMax((int*)&x1[gcur * NHID + lane * 2 + 1], __float_as_int(v1));
}

// ---------------------------------------------------------------- roots = searchsorted(batch, g)
__global__ void find_roots(const int* __restrict__ batch, int* __restrict__ roots, int N, int G) {
    int g = blockIdx.x * blockDim.x + threadIdx.x;
    if (g >= G) return;
    int lo = 0, hi = N;
    while (lo < hi) { int mid = (lo + hi) >> 1; if (batch[mid] < g) lo = mid + 1; else hi = mid; }
    roots[g] = min(lo, N - 1);   // jnp gather clamps OOB the same way
}

// ---------------------------------------------------------------- news = relu(x[roots] @ W0 + b0)
__global__ __launch_bounds__(128) void news_k(const float* __restrict__ x,
                                              const int* __restrict__ roots,
                                              const float* __restrict__ W0,
                                              const float* __restrict__ b0,
                                              float* __restrict__ news) {
    __shared__ float xr[NFEAT];
    int g = blockIdx.x, t = threadIdx.x;
    const float* xp = x + (size_t)roots[g] * NFEAT;
    for (int i = t; i < NFEAT; i += 128) xr[i] = xp[i];
    __syncthreads();
    float acc = b0[t];
#pragma unroll 8
    for (int k = 0; k < NFEAT; ++k) acc += xr[k] * W0[(size_t)k * NHID + t];
    news[(size_t)g * NHID + t] = fmaxf(acc, 0.f);
}

// ---------------------------------------------------------------- head: z, logits, log_softmax
__global__ __launch_bounds__(128) void head_k(const float* __restrict__ x1,
                                              const float* __restrict__ news,
                                              const float* __restrict__ W1,
                                              const float* __restrict__ b1,
                                              const float* __restrict__ W2,
                                              const float* __restrict__ b2,
                                              float* __restrict__ logp0,
                                              float* __restrict__ logp1) {
    __shared__ float zin[2 * NHID];
    __shared__ float z[NHID];
    __shared__ float lg[2];
    int g = blockIdx.x, t = threadIdx.x;
    zin[t] = x1[(size_t)g * NHID + t];
    zin[NHID + t] = news[(size_t)g * NHID + t];
    __syncthreads();
    float acc = b1[t];
#pragma unroll 8
    for (int k = 0; k < 2 * NHID; ++k) acc += zin[k] * W1[(size_t)k * NHID + t];
    z[t] = fmaxf(acc, 0.f);
    __syncthreads();
    if (t < 2) {
        float a = b2[t];
        for (int k = 0; k < NHID; ++k) a += z[k] * W2[k * 2 + t];
        lg[t] = a;
    }
    __syncthreads();
    if (t == 0) {
        float mx = fmaxf(lg[0], lg[1]);
        float lse = mx + logf(expf(lg[0] - mx) + expf(lg[1] - mx));
        float p0 = lg[0] - lse, p1 = lg[1] - lse;
        logp0[g * 2] = p0; logp0[g * 2 + 1] = p1;
        logp1[g * 2] = p0; logp1[g * 2 + 1] = p1;
    }
}

// ----------------------------------------------------------------
extern "C" void kernel_launch(void* const* d_in, const int* in_sizes, int n_in,
                              void* d_out, int out_size, void* d_ws, size_t ws_size,
                              hipStream_t stream) {
    const float* x        = (const float*)d_in[0];
    const int*   eidx     = (const int*)d_in[1];
    const int*   batch    = (const int*)d_in[2];
    const float* W        = (const float*)d_in[4];
    const float* att_src  = (const float*)d_in[5];
    const float* att_dst  = (const float*)d_in[6];
    const float* b_conv   = (const float*)d_in[7];
    const float* W0       = (const float*)d_in[8];
    const float* b0       = (const float*)d_in[9];
    const float* W1       = (const float*)d_in[10];
    const float* b1       = (const float*)d_in[11];
    const float* W2       = (const float*)d_in[12];
    const float* b2       = (const float*)d_in[13];

    const int N = in_sizes[2];
    const int E = in_sizes[1] / 2;
    const int G = out_size / (2 + NHID + 2);
    const int T = E + N;

    char* ws = (char*)d_ws;
    size_t o = 0;
    auto alloc = [&](size_t bytes) -> char* {
        char* p = ws + o; o += (bytes + 255) & ~(size_t)255; return p;
    };
    unsigned short* hbf  = (unsigned short*)alloc((size_t)N * NHID * 2);
    float* hrelu         = (float*)alloc((size_t)N * NHID * 4);
    float* a_src         = (float*)alloc((size_t)N * 4);
    float* a_dst         = (float*)alloc((size_t)N * 4);
    unsigned short* Wt   = (unsigned short*)alloc((size_t)NHID * NFEAT * 2);
    int* deg             = (int*)alloc((size_t)N * 4);
    int* off             = (int*)alloc((size_t)N * 4);
    int* cursor          = (int*)alloc((size_t)N * 4);
    int* csr             = (int*)alloc((size_t)T * 4);
    int* bsum            = (int*)alloc(1024 * 4);
    int* boff            = (int*)alloc(1024 * 4);
    int* roots           = (int*)alloc((size_t)G * 4);
    float* news          = (float*)alloc((size_t)G * NHID * 4);

    float* out_logp  = (float*)d_out;
    float* out_x1    = out_logp + 2 * G;
    float* out_logp2 = out_x1 + (size_t)G * NHID;

    hipMemsetAsync(d_out, 0, (size_t)out_size * 4, stream);
    hipMemsetAsync(deg, 0, (size_t)N * 4, stream);

    prep_wt<<<(NFEAT * NHID + 255) / 256, 256, 0, stream>>>(W, Wt);
    gemm_xw<<<(N + 127) / 128, 256, 0, stream>>>(x, Wt, hbf, N);
    attn_proj<<<1024, 256, 0, stream>>>(hbf, att_src, att_dst, a_src, a_dst, N);
    count_k<<<(T + 255) / 256, 256, 0, stream>>>(eidx + E, deg, E, N);
    int nb1 = (N + 1023) / 1024;
    scan1_k<<<nb1, 256, 0, stream>>>(deg, off, bsum, N);
    scan2_k<<<1, 128, 0, stream>>>(bsum, boff, nb1);
    scan3_k<<<(N + 255) / 256, 256, 0, stream>>>(off, boff, cursor, N);
    fill_k<<<(T + 255) / 256, 256, 0, stream>>>(eidx, eidx + E, cursor, csr, E, N);
    aggregate_k<<<(N + 3) / 4, 256, 0, stream>>>(off, deg, csr, a_src, a_dst, hbf, b_conv, hrelu, N);
    pool_max<<<(N + 255) / 256, 256, 0, stream>>>(hrelu, batch, out_x1, N);
    find_roots<<<1, 128, 0, stream>>>(batch, roots, N, G);
    news_k<<<G, 128, 0, stream>>>(x, roots, W0, b0, news);
    head_k<<<G, 128, 0, stream>>>(out_x1, news, W1, b1, W2, b2, out_logp, out_logp2);
}

// Round 2
// 563.488 us; speedup vs baseline: 1.2034x; 1.2034x over previous
//
#include <hip/hip_runtime.h>
#include <hip/hip_bf16.h>

#define NFEAT 768
#define NHID 128
#define NEG_SLOPE 0.2f
#define SM_EPS 1e-16f
#define CAP 96   // per-wave LDS stash capacity; deg ~ Poisson(17), max << 96

typedef __attribute__((ext_vector_type(8))) short bf16x8s;
typedef __attribute__((ext_vector_type(4))) float f32x4;

__device__ inline float bf2f(unsigned short u) {
    return __uint_as_float(((unsigned int)u) << 16);
}
__device__ inline unsigned short f2bf(float f) {
    unsigned int u = __float_as_uint(f);
    u += 0x7fffu + ((u >> 16) & 1u);   // round-to-nearest-even
    return (unsigned short)(u >> 16);
}

// ---------------------------------------------------------------- prep: W^T -> bf16
__global__ void prep_wt(const float* __restrict__ W, unsigned short* __restrict__ Wt) {
    int idx = blockIdx.x * 256 + threadIdx.x;       // over 768*128
    if (idx >= NFEAT * NHID) return;
    int k = idx >> 7, n = idx & 127;
    Wt[(size_t)n * NFEAT + k] = f2bf(W[idx]);
}

// ---------------------------------------------------------------- h = x @ W  (bf16 MFMA)
// block 256 = 4 waves (2x2), tile 128x128, BK=32, LDS stride 40 (pad)
__global__ __launch_bounds__(256) void gemm_xw(const float* __restrict__ x,
                                               const unsigned short* __restrict__ Wt,
                                               unsigned short* __restrict__ hbf, int M) {
    __shared__ unsigned short As[128 * 40];
    __shared__ unsigned short Bs[128 * 40];
    const int tid = threadIdx.x;
    const int lane = tid & 63;
    const int wid = tid >> 6;
    const int wr = wid >> 1, wc = wid & 1;
    const int m0 = blockIdx.x * 128;

    f32x4 acc[4][4] = {};

    const int ar = tid >> 3;          // 0..31
    const int ac = (tid & 7) * 4;     // 0..28
    const int br = tid >> 2;          // 0..63
    const int bc = (tid & 3) * 8;     // 0..24

    for (int k0 = 0; k0 < NFEAT; k0 += 32) {
        // stage A (128x32 fp32 -> bf16)
#pragma unroll
        for (int p = 0; p < 4; ++p) {
            int r = ar + p * 32;
            int gr = m0 + r;
            float4 v;
            if (gr < M) v = *(const float4*)(x + (size_t)gr * NFEAT + k0 + ac);
            else        v = make_float4(0.f, 0.f, 0.f, 0.f);
            ushort4 b;
            b.x = f2bf(v.x); b.y = f2bf(v.y); b.z = f2bf(v.z); b.w = f2bf(v.w);
            *(ushort4*)(&As[r * 40 + ac]) = b;
        }
        // stage B: Wt rows = output cols, contiguous K
#pragma unroll
        for (int p = 0; p < 2; ++p) {
            int r = br + p * 64;
            *(int4*)(&Bs[r * 40 + bc]) = *(const int4*)(Wt + (size_t)r * NFEAT + k0 + bc);
        }
        __syncthreads();

        bf16x8s af[4], bfr[4];
        const int kh = (lane >> 4) * 8;
        const int rr = lane & 15;
#pragma unroll
        for (int m = 0; m < 4; ++m)
            af[m] = *(const bf16x8s*)(&As[(wr * 64 + m * 16 + rr) * 40 + kh]);
#pragma unroll
        for (int n = 0; n < 4; ++n)
            bfr[n] = *(const bf16x8s*)(&Bs[(wc * 64 + n * 16 + rr) * 40 + kh]);
#pragma unroll
        for (int m = 0; m < 4; ++m)
#pragma unroll
            for (int n = 0; n < 4; ++n)
                acc[m][n] = __builtin_amdgcn_mfma_f32_16x16x32_bf16(af[m], bfr[n], acc[m][n], 0, 0, 0);
        __syncthreads();
    }

    const int crow = (lane >> 4) * 4;
    const int ccol = lane & 15;
#pragma unroll
    for (int m = 0; m < 4; ++m) {
#pragma unroll
        for (int j = 0; j < 4; ++j) {
            int gr = m0 + wr * 64 + m * 16 + crow + j;
            if (gr < M) {
#pragma unroll
                for (int n = 0; n < 4; ++n)
                    hbf[(size_t)gr * NHID + wc * 64 + n * 16 + ccol] = f2bf(acc[m][n][j]);
            }
        }
    }
}

// ---------------------------------------------------------------- a_src/a_dst = h . att
__global__ __launch_bounds__(256) void attn_proj(const unsigned short* __restrict__ hbf,
                                                 const float* __restrict__ att_src,
                                                 const float* __restrict__ att_dst,
                                                 float* __restrict__ a_src, float* __restrict__ a_dst,
                                                 int N) {
    int gw = (blockIdx.x * 256 + threadIdx.x) >> 6;
    int lane = threadIdx.x & 63;
    int nw = (gridDim.x * 256) >> 6;
    float as0 = att_src[lane * 2], as1 = att_src[lane * 2 + 1];
    float ad0 = att_dst[lane * 2], ad1 = att_dst[lane * 2 + 1];
    for (int row = gw; row < N; row += nw) {
        ushort2 hv = *(const ushort2*)(hbf + (size_t)row * NHID + lane * 2);
        float h0 = bf2f(hv.x), h1 = bf2f(hv.y);
        float ps = h0 * as0 + h1 * as1;
        float pd = h0 * ad0 + h1 * ad1;
        for (int d = 32; d; d >>= 1) { ps += __shfl_xor(ps, d); pd += __shfl_xor(pd, d); }
        if (lane == 0) { a_src[row] = ps; a_dst[row] = pd; }
    }
}

// ---------------------------------------------------------------- CSR build
__global__ void count_k(const int* __restrict__ edst, int* __restrict__ deg, int E, int N) {
    int i = blockIdx.x * 256 + threadIdx.x;
    if (i >= E + N) return;
    int d = (i < E) ? edst[i] : (i - E);
    atomicAdd(deg + d, 1);
}

__global__ void scan1_k(const int* __restrict__ deg, int* __restrict__ off,
                        int* __restrict__ bsum, int N) {
    __shared__ int s[256];
    int b = blockIdx.x, t = threadIdx.x;
    int base = b * 1024 + t * 4;
    int v[4]; int sum = 0;
#pragma unroll
    for (int i = 0; i < 4; ++i) { int idx = base + i; v[i] = (idx < N) ? deg[idx] : 0; sum += v[i]; }
    s[t] = sum; __syncthreads();
    for (int d = 1; d < 256; d <<= 1) {
        int xo = (t >= d) ? s[t - d] : 0;
        __syncthreads();
        s[t] += xo;
        __syncthreads();
    }
    int run = s[t] - sum;               // exclusive prefix within block
    if (t == 255) bsum[b] = s[255];
#pragma unroll
    for (int i = 0; i < 4; ++i) { int idx = base + i; if (idx < N) off[idx] = run; run += v[i]; }
}

__global__ void scan2_k(const int* __restrict__ bsum, int* __restrict__ boff, int nb) {
    __shared__ int s[128];
    int t = threadIdx.x;
    int v = (t < nb) ? bsum[t] : 0;
    s[t] = v; __syncthreads();
    for (int d = 1; d < 128; d <<= 1) {
        int xo = (t >= d) ? s[t - d] : 0;
        __syncthreads();
        s[t] += xo;
        __syncthreads();
    }
    if (t < nb) boff[t] = s[t] - v;
}

__global__ void scan3_k(int* __restrict__ off, const int* __restrict__ boff,
                        int* __restrict__ cursor, int N) {
    int i = blockIdx.x * 256 + threadIdx.x;
    if (i >= N) return;
    int v = off[i] + boff[i >> 10];
    off[i] = v; cursor[i] = v;
}

__global__ void fill_k(const int* __restrict__ esrc, const int* __restrict__ edst,
                       int* __restrict__ cursor, int* __restrict__ csr, int E, int N) {
    int i = blockIdx.x * 256 + threadIdx.x;
    if (i >= E + N) return;
    int s, d;
    if (i < E) { s = esrc[i]; d = edst[i]; } else { s = i - E; d = i - E; }
    int pos = atomicAdd(cursor + d, 1);
    csr[pos] = s;
}

// ---------------------------------------------------------------- segment softmax + aggregate
// one wave per destination node.
// Phase 1 (lanes || edges): e -> LDS, wave-max.  Phase 2: w=exp(e-m) -> LDS, wave-sum denom.
// Phase 3 (serial edges, lanes || features): pure {ds_read, 4B gather, 2 FMA} loop.
__global__ __launch_bounds__(256) void aggregate_k(const int* __restrict__ off,
                                                   const int* __restrict__ deg,
                                                   const int* __restrict__ csr,
                                                   const float* __restrict__ a_src,
                                                   const float* __restrict__ a_dst,
                                                   const unsigned short* __restrict__ hbf,
                                                   const float* __restrict__ b_conv,
                                                   float* __restrict__ hrelu, int N) {
    __shared__ int   ssh[4][CAP];
    __shared__ float wsh[4][CAP];
    int wid = threadIdx.x >> 6, lane = threadIdx.x & 63;
    int dst = blockIdx.x * 4 + wid;
    if (dst >= N) return;
    int start = off[dst], cnt = deg[dst];
    float ad = a_dst[dst];

    // phase 1: stash (src, e), wave-max
    float m = -1e30f;
    for (int j = lane; j < cnt; j += 64) {
        int s = csr[start + j];
        float e = a_src[s] + ad;
        e = e > 0.f ? e : NEG_SLOPE * e;
        if (j < CAP) { ssh[wid][j] = s; wsh[wid][j] = e; }
        m = fmaxf(m, e);
    }
#pragma unroll
    for (int d = 32; d; d >>= 1) m = fmaxf(m, __shfl_xor(m, d));

    // phase 2: w = exp(e-m) (hw exp), stash, wave-sum denom
    float denom = 0.f;
    for (int j = lane; j < cnt; j += 64) {
        float e;
        if (j < CAP) e = wsh[wid][j];
        else {
            int s = csr[start + j];
            e = a_src[s] + ad;
            e = e > 0.f ? e : NEG_SLOPE * e;
        }
        float w = __expf(e - m);
        if (j < CAP) wsh[wid][j] = w;
        denom += w;
    }
#pragma unroll
    for (int d = 32; d; d >>= 1) denom += __shfl_xor(denom, d);

    // phase 3: lean gather+FMA loop (wave-synchronous LDS, no barrier needed)
    float acc0 = 0.f, acc1 = 0.f;
    const unsigned short* hp = hbf + lane * 2;
    if (cnt <= CAP) {
        int j = 0;
        for (; j + 1 < cnt; j += 2) {
            int s0 = ssh[wid][j];     float w0 = wsh[wid][j];
            int s1 = ssh[wid][j + 1]; float w1 = wsh[wid][j + 1];
            ushort2 h0 = *(const ushort2*)(hp + (size_t)s0 * NHID);
            ushort2 h1 = *(const ushort2*)(hp + (size_t)s1 * NHID);
            acc0 += w0 * bf2f(h0.x); acc1 += w0 * bf2f(h0.y);
            acc0 += w1 * bf2f(h1.x); acc1 += w1 * bf2f(h1.y);
        }
        if (j < cnt) {
            int s0 = ssh[wid][j]; float w0 = wsh[wid][j];
            ushort2 h0 = *(const ushort2*)(hp + (size_t)s0 * NHID);
            acc0 += w0 * bf2f(h0.x); acc1 += w0 * bf2f(h0.y);
        }
    } else {
        for (int j = 0; j < cnt; ++j) {
            int s; float w;
            if (j < CAP) { s = ssh[wid][j]; w = wsh[wid][j]; }
            else {
                s = csr[start + j];
                float e = a_src[s] + ad;
                e = e > 0.f ? e : NEG_SLOPE * e;
                w = __expf(e - m);
            }
            ushort2 hv = *(const ushort2*)(hp + (size_t)s * NHID);
            acc0 += w * bf2f(hv.x); acc1 += w * bf2f(hv.y);
        }
    }
    float inv = 1.f / (denom + SM_EPS);
    float o0 = acc0 * inv + b_conv[lane * 2];
    float o1 = acc1 * inv + b_conv[lane * 2 + 1];
    hrelu[(size_t)dst * NHID + lane * 2]     = fmaxf(o0, 0.f);
    hrelu[(size_t)dst * NHID + lane * 2 + 1] = fmaxf(o1, 0.f);
}

// ---------------------------------------------------------------- global max pool (batch sorted)
__global__ __launch_bounds__(256) void pool_max(const float* __restrict__ hrelu,
                                                const int* __restrict__ batch,
                                                float* __restrict__ x1, int N) {
    int wid = threadIdx.x >> 6, lane = threadIdx.x & 63;
    int n0 = blockIdx.x * 256 + wid * 64;
    if (n0 >= N) return;
    int gcur = batch[n0];
    float v0 = 0.f, v1 = 0.f;
    int end = min(n0 + 64, N);
    for (int n = n0; n < end; ++n) {
        int g = batch[n];
        if (g != gcur) {
            atomicMax((int*)&x1[gcur * NHID + lane * 2],     __float_as_int(v0));
            atomicMax((int*)&x1[gcur * NHID + lane * 2 + 1], __float_as_int(v1));
            v0 = v1 = 0.f; gcur = g;
        }
        float2 hv = *(const float2*)(hrelu + (size_t)n * NHID + lane * 2);
        v0 = fmaxf(v0, hv.x); v1 = fmaxf(v1, hv.y);
    }
    atomicMax((int*)&x1[gcur * NHID + lane * 2],     __float_as_int(v0));
    atomicMax((int*)&x1[gcur * NHID + lane * 2 + 1], __float_as_int(v1));
}

// ---------------------------------------------------------------- roots = searchsorted(batch, g)
__global__ void find_roots(const int* __restrict__ batch, int* __restrict__ roots, int N, int G) {
    int g = blockIdx.x * blockDim.x + threadIdx.x;
    if (g >= G) return;
    int lo = 0, hi = N;
    while (lo < hi) { int mid = (lo + hi) >> 1; if (batch[mid] < g) lo = mid + 1; else hi = mid; }
    roots[g] = min(lo, N - 1);   // jnp gather clamps OOB the same way
}

// ---------------------------------------------------------------- news = relu(x[roots] @ W0 + b0)
__global__ __launch_bounds__(128) void news_k(const float* __restrict__ x,
                                              const int* __restrict__ roots,
                                              const float* __restrict__ W0,
                                              const float* __restrict__ b0,
                                              float* __restrict__ news) {
    __shared__ float xr[NFEAT];
    int g = blockIdx.x, t = threadIdx.x;
    const float* xp = x + (size_t)roots[g] * NFEAT;
    for (int i = t; i < NFEAT; i += 128) xr[i] = xp[i];
    __syncthreads();
    float acc = b0[t];
#pragma unroll 8
    for (int k = 0; k < NFEAT; ++k) acc += xr[k] * W0[(size_t)k * NHID + t];
    news[(size_t)g * NHID + t] = fmaxf(acc, 0.f);
}

// ---------------------------------------------------------------- head: z, logits, log_softmax
__global__ __launch_bounds__(128) void head_k(const float* __restrict__ x1,
                                              const float* __restrict__ news,
                                              const float* __restrict__ W1,
                                              const float* __restrict__ b1,
                                              const float* __restrict__ W2,
                                              const float* __restrict__ b2,
                                              float* __restrict__ logp0,
                                              float* __restrict__ logp1) {
    __shared__ float zin[2 * NHID];
    __shared__ float z[NHID];
    __shared__ float lg[2];
    int g = blockIdx.x, t = threadIdx.x;
    zin[t] = x1[(size_t)g * NHID + t];
    zin[NHID + t] = news[(size_t)g * NHID + t];
    __syncthreads();
    float acc = b1[t];
#pragma unroll 8
    for (int k = 0; k < 2 * NHID; ++k) acc += zin[k] * W1[(size_t)k * NHID + t];
    z[t] = fmaxf(acc, 0.f);
    __syncthreads();
    if (t < 2) {
        float a = b2[t];
        for (int k = 0; k < NHID; ++k) a += z[k] * W2[k * 2 + t];
        lg[t] = a;
    }
    __syncthreads();
    if (t == 0) {
        float mx = fmaxf(lg[0], lg[1]);
        float lse = mx + logf(expf(lg[0] - mx) + expf(lg[1] - mx));
        float p0 = lg[0] - lse, p1 = lg[1] - lse;
        logp0[g * 2] = p0; logp0[g * 2 + 1] = p1;
        logp1[g * 2] = p0; logp1[g * 2 + 1] = p1;
    }
}

// ----------------------------------------------------------------
extern "C" void kernel_launch(void* const* d_in, const int* in_sizes, int n_in,
                              void* d_out, int out_size, void* d_ws, size_t ws_size,
                              hipStream_t stream) {
    const float* x        = (const float*)d_in[0];
    const int*   eidx     = (const int*)d_in[1];
    const int*   batch    = (const int*)d_in[2];
    const float* W        = (const float*)d_in[4];
    const float* att_src  = (const float*)d_in[5];
    const float* att_dst  = (const float*)d_in[6];
    const float* b_conv   = (const float*)d_in[7];
    const float* W0       = (const float*)d_in[8];
    const float* b0       = (const float*)d_in[9];
    const float* W1       = (const float*)d_in[10];
    const float* b1       = (const float*)d_in[11];
    const float* W2       = (const float*)d_in[12];
    const float* b2       = (const float*)d_in[13];

    const int N = in_sizes[2];
    const int E = in_sizes[1] / 2;
    const int G = out_size / (2 + NHID + 2);
    const int T = E + N;

    char* ws = (char*)d_ws;
    size_t o = 0;
    auto alloc = [&](size_t bytes) -> char* {
        char* p = ws + o; o += (bytes + 255) & ~(size_t)255; return p;
    };
    unsigned short* hbf  = (unsigned short*)alloc((size_t)N * NHID * 2);
    float* hrelu         = (float*)alloc((size_t)N * NHID * 4);
    float* a_src         = (float*)alloc((size_t)N * 4);
    float* a_dst         = (float*)alloc((size_t)N * 4);
    unsigned short* Wt   = (unsigned short*)alloc((size_t)NHID * NFEAT * 2);
    int* deg             = (int*)alloc((size_t)N * 4);
    int* off             = (int*)alloc((size_t)N * 4);
    int* cursor          = (int*)alloc((size_t)N * 4);
    int* csr             = (int*)alloc((size_t)T * 4);
    int* bsum            = (int*)alloc(1024 * 4);
    int* boff            = (int*)alloc(1024 * 4);
    int* roots           = (int*)alloc((size_t)G * 4);
    float* news          = (float*)alloc((size_t)G * NHID * 4);

    float* out_logp  = (float*)d_out;
    float* out_x1    = out_logp + 2 * G;
    float* out_logp2 = out_x1 + (size_t)G * NHID;

    hipMemsetAsync(d_out, 0, (size_t)out_size * 4, stream);
    hipMemsetAsync(deg, 0, (size_t)N * 4, stream);

    prep_wt<<<(NFEAT * NHID + 255) / 256, 256, 0, stream>>>(W, Wt);
    gemm_xw<<<(N + 127) / 128, 256, 0, stream>>>(x, Wt, hbf, N);
    attn_proj<<<1024, 256, 0, stream>>>(hbf, att_src, att_dst, a_src, a_dst, N);
    count_k<<<(T + 255) / 256, 256, 0, stream>>>(eidx + E, deg, E, N);
    int nb1 = (N + 1023) / 1024;
    scan1_k<<<nb1, 256, 0, stream>>>(deg, off, bsum, N);
    scan2_k<<<1, 128, 0, stream>>>(bsum, boff, nb1);
    scan3_k<<<(N + 255) / 256, 256, 0, stream>>>(off, boff, cursor, N);
    fill_k<<<(T + 255) / 256, 256, 0, stream>>>(eidx, eidx + E, cursor, csr, E, N);
    aggregate_k<<<(N + 3) / 4, 256, 0, stream>>>(off, deg, csr, a_src, a_dst, hbf, b_conv, hrelu, N);
    pool_max<<<(N + 255) / 256, 256, 0, stream>>>(hrelu, batch, out_x1, N);
    find_roots<<<1, 128, 0, stream>>>(batch, roots, N, G);
    news_k<<<G, 128, 0, stream>>>(x, roots, W0, b0, news);
    head_k<<<G, 128, 0, stream>>>(out_x1, news, W1, b1, W2, b2, out_logp, out_logp2);
}

// Round 3
// 554.950 us; speedup vs baseline: 1.2219x; 1.0154x over previous
//
#include <hip/hip_runtime.h>
#include <hip/hip_bf16.h>

#define NFEAT 768
#define NHID 128
#define NEG_SLOPE 0.2f
#define SM_EPS 1e-16f
#define CAP 96   // per-wave LDS stash capacity; deg ~ Poisson(17), max << 96

typedef __attribute__((ext_vector_type(8))) short bf16x8s;
typedef __attribute__((ext_vector_type(4))) float f32x4;

__device__ inline float bf2f(unsigned short u) {
    return __uint_as_float(((unsigned int)u) << 16);
}
__device__ inline unsigned short f2bf(float f) {
    unsigned int u = __float_as_uint(f);
    u += 0x7fffu + ((u >> 16) & 1u);   // round-to-nearest-even
    return (unsigned short)(u >> 16);
}
__device__ inline bf16x8s cvt8(float4 a, float4 b) {
    bf16x8s r;
    r[0] = (short)f2bf(a.x); r[1] = (short)f2bf(a.y);
    r[2] = (short)f2bf(a.z); r[3] = (short)f2bf(a.w);
    r[4] = (short)f2bf(b.x); r[5] = (short)f2bf(b.y);
    r[6] = (short)f2bf(b.z); r[7] = (short)f2bf(b.w);
    return r;
}

// ---------------------------------------------------------------- prep: W^T -> bf16
__global__ void prep_wt(const float* __restrict__ W, unsigned short* __restrict__ Wt) {
    int idx = blockIdx.x * 256 + threadIdx.x;       // over 768*128
    if (idx >= NFEAT * NHID) return;
    int k = idx >> 7, n = idx & 127;
    Wt[(size_t)n * NFEAT + k] = f2bf(W[idx]);
}

// ---------------------------------------------------------------- h = x @ W  (bf16 MFMA)
// Barrier-free, LDS-free: one wave owns 32 rows x 128 cols.
// A-frag (16x32) loaded directly from x: lane reads row (lane&15), k-chunk (lane>>4)*8.
// B-frag loaded directly from L2-resident Wt (col-major rows = output cols).
__global__ __launch_bounds__(256) void gemm_xw(const float* __restrict__ x,
                                               const unsigned short* __restrict__ Wt,
                                               unsigned short* __restrict__ hbf, int M) {
    const int lane = threadIdx.x & 63;
    const int wv = (blockIdx.x * 256 + threadIdx.x) >> 6;   // global wave id
    const int r0 = wv * 32;
    if (r0 >= M) return;

    const int rl = lane & 15;
    const int kc = (lane >> 4) * 8;
    const float* a0p = x + (size_t)(r0 + rl) * NFEAT + kc;
    const float* a1p = a0p + (size_t)16 * NFEAT;
    const unsigned short* bp = Wt + (size_t)rl * NFEAT + kc;

    f32x4 acc[2][8] = {};

#pragma unroll 2
    for (int k0 = 0; k0 < NFEAT; k0 += 32) {
        float4 v0a = *(const float4*)(a0p);
        float4 v0b = *(const float4*)(a0p + 4);
        float4 v1a = *(const float4*)(a1p);
        float4 v1b = *(const float4*)(a1p + 4);
        bf16x8s bfr[8];
#pragma unroll
        for (int nf = 0; nf < 8; ++nf)
            bfr[nf] = *(const bf16x8s*)(bp + (size_t)nf * 16 * NFEAT);
        bf16x8s a0 = cvt8(v0a, v0b);
        bf16x8s a1 = cvt8(v1a, v1b);
#pragma unroll
        for (int nf = 0; nf < 8; ++nf) {
            acc[0][nf] = __builtin_amdgcn_mfma_f32_16x16x32_bf16(a0, bfr[nf], acc[0][nf], 0, 0, 0);
            acc[1][nf] = __builtin_amdgcn_mfma_f32_16x16x32_bf16(a1, bfr[nf], acc[1][nf], 0, 0, 0);
        }
        a0p += 32; a1p += 32; bp += 32;
    }

    const int cr = (lane >> 4) * 4;
    const int cc = lane & 15;
#pragma unroll
    for (int m = 0; m < 2; ++m) {
#pragma unroll
        for (int j = 0; j < 4; ++j) {
            size_t rowoff = (size_t)(r0 + m * 16 + cr + j) * NHID;
#pragma unroll
            for (int nf = 0; nf < 8; ++nf)
                hbf[rowoff + nf * 16 + cc] = f2bf(acc[m][nf][j]);
        }
    }
}

// ---------------------------------------------------------------- a_src/a_dst = h . att
__global__ __launch_bounds__(256) void attn_proj(const unsigned short* __restrict__ hbf,
                                                 const float* __restrict__ att_src,
                                                 const float* __restrict__ att_dst,
                                                 float* __restrict__ a_src, float* __restrict__ a_dst,
                                                 int N) {
    int gw = (blockIdx.x * 256 + threadIdx.x) >> 6;
    int lane = threadIdx.x & 63;
    int nw = (gridDim.x * 256) >> 6;
    float as0 = att_src[lane * 2], as1 = att_src[lane * 2 + 1];
    float ad0 = att_dst[lane * 2], ad1 = att_dst[lane * 2 + 1];
    for (int row = gw; row < N; row += nw) {
        ushort2 hv = *(const ushort2*)(hbf + (size_t)row * NHID + lane * 2);
        float h0 = bf2f(hv.x), h1 = bf2f(hv.y);
        float ps = h0 * as0 + h1 * as1;
        float pd = h0 * ad0 + h1 * ad1;
        for (int d = 32; d; d >>= 1) { ps += __shfl_xor(ps, d); pd += __shfl_xor(pd, d); }
        if (lane == 0) { a_src[row] = ps; a_dst[row] = pd; }
    }
}

// ---------------------------------------------------------------- CSR build
__global__ void count_k(const int* __restrict__ edst, int* __restrict__ deg, int E, int N) {
    int i = blockIdx.x * 256 + threadIdx.x;
    if (i >= E + N) return;
    int d = (i < E) ? edst[i] : (i - E);
    atomicAdd(deg + d, 1);
}

__global__ void scan1_k(const int* __restrict__ deg, int* __restrict__ off,
                        int* __restrict__ bsum, int N) {
    __shared__ int s[256];
    int b = blockIdx.x, t = threadIdx.x;
    int base = b * 1024 + t * 4;
    int v[4]; int sum = 0;
#pragma unroll
    for (int i = 0; i < 4; ++i) { int idx = base + i; v[i] = (idx < N) ? deg[idx] : 0; sum += v[i]; }
    s[t] = sum; __syncthreads();
    for (int d = 1; d < 256; d <<= 1) {
        int xo = (t >= d) ? s[t - d] : 0;
        __syncthreads();
        s[t] += xo;
        __syncthreads();
    }
    int run = s[t] - sum;               // exclusive prefix within block
    if (t == 255) bsum[b] = s[255];
#pragma unroll
    for (int i = 0; i < 4; ++i) { int idx = base + i; if (idx < N) off[idx] = run; run += v[i]; }
}

__global__ void scan2_k(const int* __restrict__ bsum, int* __restrict__ boff, int nb) {
    __shared__ int s[128];
    int t = threadIdx.x;
    int v = (t < nb) ? bsum[t] : 0;
    s[t] = v; __syncthreads();
    for (int d = 1; d < 128; d <<= 1) {
        int xo = (t >= d) ? s[t - d] : 0;
        __syncthreads();
        s[t] += xo;
        __syncthreads();
    }
    if (t < nb) boff[t] = s[t] - v;
}

__global__ void scan3_k(int* __restrict__ off, const int* __restrict__ boff,
                        int* __restrict__ cursor, int N) {
    int i = blockIdx.x * 256 + threadIdx.x;
    if (i >= N) return;
    int v = off[i] + boff[i >> 10];
    off[i] = v; cursor[i] = v;
}

__global__ void fill_k(const int* __restrict__ esrc, const int* __restrict__ edst,
                       int* __restrict__ cursor, int* __restrict__ csr, int E, int N) {
    int i = blockIdx.x * 256 + threadIdx.x;
    if (i >= E + N) return;
    int s, d;
    if (i < E) { s = esrc[i]; d = edst[i]; } else { s = i - E; d = i - E; }
    int pos = atomicAdd(cursor + d, 1);
    csr[pos] = s;
}

// ---------------------------------------------------------------- segment softmax + aggregate
// one wave per destination node.
// Phase 1 (lanes || edges): e -> LDS, wave-max.  Phase 2: w=exp(e-m) -> LDS, wave-sum denom.
// Phase 3 (serial edges, lanes || features): pure {ds_read, 4B gather, 2 FMA} loop.
__global__ __launch_bounds__(256) void aggregate_k(const int* __restrict__ off,
                                                   const int* __restrict__ deg,
                                                   const int* __restrict__ csr,
                                                   const float* __restrict__ a_src,
                                                   const float* __restrict__ a_dst,
                                                   const unsigned short* __restrict__ hbf,
                                                   const float* __restrict__ b_conv,
                                                   float* __restrict__ hrelu, int N) {
    __shared__ int   ssh[4][CAP];
    __shared__ float wsh[4][CAP];
    int wid = threadIdx.x >> 6, lane = threadIdx.x & 63;
    int dst = blockIdx.x * 4 + wid;
    if (dst >= N) return;
    int start = off[dst], cnt = deg[dst];
    float ad = a_dst[dst];

    // phase 1: stash (src, e), wave-max
    float m = -1e30f;
    for (int j = lane; j < cnt; j += 64) {
        int s = csr[start + j];
        float e = a_src[s] + ad;
        e = e > 0.f ? e : NEG_SLOPE * e;
        if (j < CAP) { ssh[wid][j] = s; wsh[wid][j] = e; }
        m = fmaxf(m, e);
    }
#pragma unroll
    for (int d = 32; d; d >>= 1) m = fmaxf(m, __shfl_xor(m, d));

    // phase 2: w = exp(e-m) (hw exp), stash, wave-sum denom
    float denom = 0.f;
    for (int j = lane; j < cnt; j += 64) {
        float e;
        if (j < CAP) e = wsh[wid][j];
        else {
            int s = csr[start + j];
            e = a_src[s] + ad;
            e = e > 0.f ? e : NEG_SLOPE * e;
        }
        float w = __expf(e - m);
        if (j < CAP) wsh[wid][j] = w;
        denom += w;
    }
#pragma unroll
    for (int d = 32; d; d >>= 1) denom += __shfl_xor(denom, d);

    // phase 3: lean gather+FMA loop (wave-synchronous LDS, no barrier needed)
    float acc0 = 0.f, acc1 = 0.f;
    const unsigned short* hp = hbf + lane * 2;
    if (cnt <= CAP) {
        int j = 0;
        for (; j + 1 < cnt; j += 2) {
            int s0 = ssh[wid][j];     float w0 = wsh[wid][j];
            int s1 = ssh[wid][j + 1]; float w1 = wsh[wid][j + 1];
            ushort2 h0 = *(const ushort2*)(hp + (size_t)s0 * NHID);
            ushort2 h1 = *(const ushort2*)(hp + (size_t)s1 * NHID);
            acc0 += w0 * bf2f(h0.x); acc1 += w0 * bf2f(h0.y);
            acc0 += w1 * bf2f(h1.x); acc1 += w1 * bf2f(h1.y);
        }
        if (j < cnt) {
            int s0 = ssh[wid][j]; float w0 = wsh[wid][j];
            ushort2 h0 = *(const ushort2*)(hp + (size_t)s0 * NHID);
            acc0 += w0 * bf2f(h0.x); acc1 += w0 * bf2f(h0.y);
        }
    } else {
        for (int j = 0; j < cnt; ++j) {
            int s; float w;
            if (j < CAP) { s = ssh[wid][j]; w = wsh[wid][j]; }
            else {
                s = csr[start + j];
                float e = a_src[s] + ad;
                e = e > 0.f ? e : NEG_SLOPE * e;
                w = __expf(e - m);
            }
            ushort2 hv = *(const ushort2*)(hp + (size_t)s * NHID);
            acc0 += w * bf2f(hv.x); acc1 += w * bf2f(hv.y);
        }
    }
    float inv = 1.f / (denom + SM_EPS);
    float o0 = acc0 * inv + b_conv[lane * 2];
    float o1 = acc1 * inv + b_conv[lane * 2 + 1];
    hrelu[(size_t)dst * NHID + lane * 2]     = fmaxf(o0, 0.f);
    hrelu[(size_t)dst * NHID + lane * 2 + 1] = fmaxf(o1, 0.f);
}

// ---------------------------------------------------------------- global max pool (batch sorted)
__global__ __launch_bounds__(256) void pool_max(const float* __restrict__ hrelu,
                                                const int* __restrict__ batch,
                                                float* __restrict__ x1, int N) {
    int wid = threadIdx.x >> 6, lane = threadIdx.x & 63;
    int n0 = blockIdx.x * 256 + wid * 64;
    if (n0 >= N) return;
    int gcur = batch[n0];
    float v0 = 0.f, v1 = 0.f;
    int end = min(n0 + 64, N);
    for (int n = n0; n < end; ++n) {
        int g = batch[n];
        if (g != gcur) {
            atomicMax((int*)&x1[gcur * NHID + lane * 2],     __float_as_int(v0));
            atomicMax((int*)&x1[gcur * NHID + lane * 2 + 1], __float_as_int(v1));
            v0 = v1 = 0.f; gcur = g;
        }
        float2 hv = *(const float2*)(hrelu + (size_t)n * NHID + lane * 2);
        v0 = fmaxf(v0, hv.x); v1 = fmaxf(v1, hv.y);
    }
    atomicMax((int*)&x1[gcur * NHID + lane * 2],     __float_as_int(v0));
    atomicMax((int*)&x1[gcur * NHID + lane * 2 + 1], __float_as_int(v1));
}

// ---------------------------------------------------------------- roots = searchsorted(batch, g)
__global__ void find_roots(const int* __restrict__ batch, int* __restrict__ roots, int N, int G) {
    int g = blockIdx.x * blockDim.x + threadIdx.x;
    if (g >= G) return;
    int lo = 0, hi = N;
    while (lo < hi) { int mid = (lo + hi) >> 1; if (batch[mid] < g) lo = mid + 1; else hi = mid; }
    roots[g] = min(lo, N - 1);   // jnp gather clamps OOB the same way
}

// ---------------------------------------------------------------- news = relu(x[roots] @ W0 + b0)
__global__ __launch_bounds__(128) void news_k(const float* __restrict__ x,
                                              const int* __restrict__ roots,
                                              const float* __restrict__ W0,
                                              const float* __restrict__ b0,
                                              float* __restrict__ news) {
    __shared__ float xr[NFEAT];
    int g = blockIdx.x, t = threadIdx.x;
    const float* xp = x + (size_t)roots[g] * NFEAT;
    for (int i = t; i < NFEAT; i += 128) xr[i] = xp[i];
    __syncthreads();
    float acc = b0[t];
#pragma unroll 8
    for (int k = 0; k < NFEAT; ++k) acc += xr[k] * W0[(size_t)k * NHID + t];
    news[(size_t)g * NHID + t] = fmaxf(acc, 0.f);
}

// ---------------------------------------------------------------- head: z, logits, log_softmax
__global__ __launch_bounds__(128) void head_k(const float* __restrict__ x1,
                                              const float* __restrict__ news,
                                              const float* __restrict__ W1,
                                              const float* __restrict__ b1,
                                              const float* __restrict__ W2,
                                              const float* __restrict__ b2,
                                              float* __restrict__ logp0,
                                              float* __restrict__ logp1) {
    __shared__ float zin[2 * NHID];
    __shared__ float z[NHID];
    __shared__ float lg[2];
    int g = blockIdx.x, t = threadIdx.x;
    zin[t] = x1[(size_t)g * NHID + t];
    zin[NHID + t] = news[(size_t)g * NHID + t];
    __syncthreads();
    float acc = b1[t];
#pragma unroll 8
    for (int k = 0; k < 2 * NHID; ++k) acc += zin[k] * W1[(size_t)k * NHID + t];
    z[t] = fmaxf(acc, 0.f);
    __syncthreads();
    if (t < 2) {
        float a = b2[t];
        for (int k = 0; k < NHID; ++k) a += z[k] * W2[k * 2 + t];
        lg[t] = a;
    }
    __syncthreads();
    if (t == 0) {
        float mx = fmaxf(lg[0], lg[1]);
        float lse = mx + logf(expf(lg[0] - mx) + expf(lg[1] - mx));
        float p0 = lg[0] - lse, p1 = lg[1] - lse;
        logp0[g * 2] = p0; logp0[g * 2 + 1] = p1;
        logp1[g * 2] = p0; logp1[g * 2 + 1] = p1;
    }
}

// ----------------------------------------------------------------
extern "C" void kernel_launch(void* const* d_in, const int* in_sizes, int n_in,
                              void* d_out, int out_size, void* d_ws, size_t ws_size,
                              hipStream_t stream) {
    const float* x        = (const float*)d_in[0];
    const int*   eidx     = (const int*)d_in[1];
    const int*   batch    = (const int*)d_in[2];
    const float* W        = (const float*)d_in[4];
    const float* att_src  = (const float*)d_in[5];
    const float* att_dst  = (const float*)d_in[6];
    const float* b_conv   = (const float*)d_in[7];
    const float* W0       = (const float*)d_in[8];
    const float* b0       = (const float*)d_in[9];
    const float* W1       = (const float*)d_in[10];
    const float* b1       = (const float*)d_in[11];
    const float* W2       = (const float*)d_in[12];
    const float* b2       = (const float*)d_in[13];

    const int N = in_sizes[2];
    const int E = in_sizes[1] / 2;
    const int G = out_size / (2 + NHID + 2);
    const int T = E + N;

    char* ws = (char*)d_ws;
    size_t o = 0;
    auto alloc = [&](size_t bytes) -> char* {
        char* p = ws + o; o += (bytes + 255) & ~(size_t)255; return p;
    };
    unsigned short* hbf  = (unsigned short*)alloc((size_t)N * NHID * 2);
    float* hrelu         = (float*)alloc((size_t)N * NHID * 4);
    float* a_src         = (float*)alloc((size_t)N * 4);
    float* a_dst         = (float*)alloc((size_t)N * 4);
    unsigned short* Wt   = (unsigned short*)alloc((size_t)NHID * NFEAT * 2);
    int* deg             = (int*)alloc((size_t)N * 4);
    int* off             = (int*)alloc((size_t)N * 4);
    int* cursor          = (int*)alloc((size_t)N * 4);
    int* csr             = (int*)alloc((size_t)T * 4);
    int* bsum            = (int*)alloc(1024 * 4);
    int* boff            = (int*)alloc(1024 * 4);
    int* roots           = (int*)alloc((size_t)G * 4);
    float* news          = (float*)alloc((size_t)G * NHID * 4);

    float* out_logp  = (float*)d_out;
    float* out_x1    = out_logp + 2 * G;
    float* out_logp2 = out_x1 + (size_t)G * NHID;

    hipMemsetAsync(d_out, 0, (size_t)out_size * 4, stream);
    hipMemsetAsync(deg, 0, (size_t)N * 4, stream);

    prep_wt<<<(NFEAT * NHID + 255) / 256, 256, 0, stream>>>(W, Wt);
    gemm_xw<<<(N + 127) / 128, 256, 0, stream>>>(x, Wt, hbf, N);
    attn_proj<<<1024, 256, 0, stream>>>(hbf, att_src, att_dst, a_src, a_dst, N);
    count_k<<<(T + 255) / 256, 256, 0, stream>>>(eidx + E, deg, E, N);
    int nb1 = (N + 1023) / 1024;
    scan1_k<<<nb1, 256, 0, stream>>>(deg, off, bsum, N);
    scan2_k<<<1, 128, 0, stream>>>(bsum, boff, nb1);
    scan3_k<<<(N + 255) / 256, 256, 0, stream>>>(off, boff, cursor, N);
    fill_k<<<(T + 255) / 256, 256, 0, stream>>>(eidx, eidx + E, cursor, csr, E, N);
    aggregate_k<<<(N + 3) / 4, 256, 0, stream>>>(off, deg, csr, a_src, a_dst, hbf, b_conv, hrelu, N);
    pool_max<<<(N + 255) / 256, 256, 0, stream>>>(hrelu, batch, out_x1, N);
    find_roots<<<1, 128, 0, stream>>>(batch, roots, N, G);
    news_k<<<G, 128, 0, stream>>>(x, roots, W0, b0, news);
    head_k<<<G, 128, 0, stream>>>(out_x1, news, W1, b1, W2, b2, out_logp, out_logp2);
}